// Round 6
// baseline (246.098 us; speedup 1.0000x reference)
//
#include <hip/hip_runtime.h>
#include <hip/hip_bf16.h>

#define B_ 32
#define S_ 4096
#define H_ 512

typedef short bf16x8 __attribute__((ext_vector_type(8)));
typedef unsigned short u16x8 __attribute__((ext_vector_type(8)));
typedef float f32x4 __attribute__((ext_vector_type(4)));

__device__ inline unsigned short f2bf(float x) {
    unsigned u = __float_as_uint(x);
    return (unsigned short)((u + 0x7fffu + ((u >> 16) & 1u)) >> 16);
}

__device__ inline float fast_tanh(float x) {
    float e = __expf(2.f * x);
    return 1.f - 2.f / (e + 1.f);
}

// async global->LDS, 16B per lane; lds base must be wave-uniform (HW adds lane*16)
__device__ __forceinline__ void stage16(const void* g, void* lds_base) {
    __builtin_amdgcn_global_load_lds(
        (const __attribute__((address_space(1))) unsigned char*)g,
        (__attribute__((address_space(3))) unsigned char*)lds_base, 16, 0, 0);
}

// ---------------------------------------------------------------------------
// Kernel 1: transpose+convert Ua[h][d] (f32) -> ua_t[d][h] (bf16, row-major)
// ---------------------------------------------------------------------------
__global__ void k_prep_ua(const float* __restrict__ Ua,
                          unsigned short* __restrict__ ua_t) {
    __shared__ float tile[32][33];
    int h0 = blockIdx.x * 32, d0 = blockIdx.y * 32;
    int tx = threadIdx.x, ty = threadIdx.y;
#pragma unroll
    for (int j = 0; j < 4; ++j)
        tile[ty + j * 8][tx] = Ua[(size_t)(h0 + ty + j * 8) * H_ + d0 + tx];
    __syncthreads();
#pragma unroll
    for (int j = 0; j < 4; ++j) {
        int dl = ty + j * 8;
        ua_t[(size_t)(d0 + dl) * H_ + h0 + tx] = f2bf(tile[tx][dl]);
    }
}

// ---------------------------------------------------------------------------
// Kernel 2: q_proj[b][d] = sum_h query[b][h] * Wa[h][d]   (fp32, tiny)
// ---------------------------------------------------------------------------
__global__ __launch_bounds__(512) void k_qproj(const float* __restrict__ query,
                                               const float* __restrict__ Wa,
                                               float* __restrict__ qproj) {
    __shared__ float q[H_];
    int b = blockIdx.x, d = threadIdx.x;
    q[d] = query[(size_t)b * H_ + d];
    __syncthreads();
    float acc = 0.f;
    for (int h = 0; h < H_; ++h)
        acc = fmaf(q[h], Wa[(size_t)h * H_ + d], acc);
    qproj[(size_t)b * H_ + d] = acc;
}

// ---------------------------------------------------------------------------
// Kernel 3: partial scores. 256 thr / 4 waves, wave tile 64x64 (2x2 waves),
// block 128(M) x 128(N), BK=64, 8 K-iters. A single-buffer LDS (reg-staged,
// f2bf in flight), B double-buffered via global_load_lds (per-lane row +
// swizzle folded into global src; LDS dest linear). Per iter: issue
// B(t+1)+A(t+1) -> compute(t) -> barrier1 -> write A(t+1) -> barrier2.
// flat grid 4096 = (b:32) x (m:32) x (nb:4), XCD-swizzled, nb fastest.
// ---------------------------------------------------------------------------
__global__ __launch_bounds__(256, 3) void k_scores(
    const float* __restrict__ keys, const unsigned short* __restrict__ ua_t,
    const float* __restrict__ qproj, const float* __restrict__ Va,
    float* __restrict__ part_sc) {
    __shared__ __align__(16) unsigned char As[16384];      // 128 rows x 128 B, swizzled
    __shared__ __align__(16) unsigned char Bs[2][16384];   // double-buffered
    __shared__ float smp[2][128];

    int tid = threadIdx.x;
    int wave = tid >> 6, lane = tid & 63;
    int lq = lane & 15, lh = lane >> 4;
    int wm = wave >> 1, wn = wave & 1;   // 2x2 wave grid, each 64x64

    // bijective XCD swizzle (4096 % 8 == 0); nb fastest so the 4 n-tiles
    // re-reading the same keys rows share one XCD's L2.
    int logical = (blockIdx.x & 7) * 512 + (blockIdx.x >> 3);
    int b  = logical >> 7;
    int m0 = ((logical >> 2) & 31) * 128;
    int nb = logical & 3;

    const float* keysb = keys + (size_t)b * S_ * H_;

    // --- A staging map: r = tid>>1 (row 0..127), hh = tid&1 (32-float half of BK span)
    int r = tid >> 1, hh = tid & 1;
    const float* aptr = keysb + (size_t)(m0 + r) * H_ + hh * 32;
    unsigned aswz = (unsigned)((r & 7) << 4);
    unsigned arow = (unsigned)(r * 128);

    // --- B staging map: 4 gload_lds per wave; issue j=wave*4+i covers rows
    // 8j..8j+7. Per-lane global addr = row (8j + lane>>3), col (lane&7)*16,
    // XOR-swizzled by ((row&7)<<4) == ((lane>>3)<<4). LDS dest linear.
    int rbl = lane >> 3;
    unsigned cb = (unsigned)(((lane & 7) * 16) ^ (rbl << 4));
    const unsigned char* uab = (const unsigned char*)ua_t;
    const unsigned char* bsrc[4];
    unsigned bdst[4];
#pragma unroll
    for (int i = 0; i < 4; ++i) {
        int j = wave * 4 + i;
        bsrc[i] = uab + ((size_t)(nb * 128 + 8 * j + rbl)) * 1024 + cb;
        bdst[i] = (unsigned)(j * 1024);
    }

    f32x4 acc[4][4];
#pragma unroll
    for (int i = 0; i < 4; ++i)
#pragma unroll
        for (int j = 0; j < 4; ++j) acc[i][j] = (f32x4){0.f, 0.f, 0.f, 0.f};

    // ---- prologue: stage tile 0 (B -> Bs[0], A -> regs -> As)
#pragma unroll
    for (int i = 0; i < 4; ++i) stage16(bsrc[i], &Bs[0][bdst[i]]);
    {
        float4 a0[8];
#pragma unroll
        for (int j = 0; j < 8; ++j) a0[j] = *(const float4*)(aptr + j * 4);
#pragma unroll
        for (int j16 = 0; j16 < 4; ++j16) {
            float4 x = a0[2 * j16], y = a0[2 * j16 + 1];
            u16x8 v;
            v[0] = f2bf(x.x); v[1] = f2bf(x.y); v[2] = f2bf(x.z); v[3] = f2bf(x.w);
            v[4] = f2bf(y.x); v[5] = f2bf(y.y); v[6] = f2bf(y.z); v[7] = f2bf(y.w);
            *(u16x8*)(As + arow + ((unsigned)(hh * 64 + j16 * 16) ^ aswz)) = v;
        }
    }
    __syncthreads();

#pragma unroll
    for (int t = 0; t < 8; ++t) {
        const int cur = t & 1, nxt = cur ^ 1;
        float4 ar[8];
        // 1) issue next-tile loads: fly across the whole compute phase
        if (t < 7) {
#pragma unroll
            for (int i = 0; i < 4; ++i)
                stage16(bsrc[i] + (t + 1) * 128, &Bs[nxt][bdst[i]]);
#pragma unroll
            for (int j = 0; j < 8; ++j)
                ar[j] = *(const float4*)(aptr + (t + 1) * 64 + j * 4);
        }
        // 2) compute tile t: 16 ds_read_b128 -> 32 MFMAs per wave
#pragma unroll
        for (int ks = 0; ks < 2; ++ks) {
            bf16x8 af[4], bv[4];
            unsigned koff = (unsigned)(ks * 64 + lh * 16);
#pragma unroll
            for (int mf = 0; mf < 4; ++mf) {
                unsigned R = (unsigned)(wm * 64 + mf * 16 + lq);
                af[mf] = *(const bf16x8*)(As + R * 128 + (koff ^ ((R & 7) << 4)));
            }
#pragma unroll
            for (int nf = 0; nf < 4; ++nf) {
                unsigned R = (unsigned)(wn * 64 + nf * 16 + lq);
                bv[nf] = *(const bf16x8*)(&Bs[cur][0] + R * 128 + (koff ^ ((R & 7) << 4)));
            }
#pragma unroll
            for (int mf = 0; mf < 4; ++mf)
#pragma unroll
                for (int nf = 0; nf < 4; ++nf)
                    acc[mf][nf] = __builtin_amdgcn_mfma_f32_16x16x32_bf16(
                        af[mf], bv[nf], acc[mf][nf], 0, 0, 0);
        }
        // 3) barrier1: all waves done reading As/Bs[cur]; B(t+1)/A-regs drained
        __syncthreads();
        // 4) convert + write A(t+1) into As, then cheap lgkm-only barrier
        if (t < 7) {
#pragma unroll
            for (int j16 = 0; j16 < 4; ++j16) {
                float4 x = ar[2 * j16], y = ar[2 * j16 + 1];
                u16x8 v;
                v[0] = f2bf(x.x); v[1] = f2bf(x.y); v[2] = f2bf(x.z); v[3] = f2bf(x.w);
                v[4] = f2bf(y.x); v[5] = f2bf(y.y); v[6] = f2bf(y.z); v[7] = f2bf(y.w);
                *(u16x8*)(As + arow + ((unsigned)(hh * 64 + j16 * 16) ^ aswz)) = v;
            }
            __syncthreads();
        }
    }

    // epilogue: partial score over this block's 128 d-columns
    float va_r[4], qp_r[4];
#pragma unroll
    for (int nf = 0; nf < 4; ++nf) {
        int n = nb * 128 + wn * 64 + nf * 16 + lq;
        va_r[nf] = Va[n];
        qp_r[nf] = qproj[(size_t)b * H_ + n];
    }
#pragma unroll
    for (int mf = 0; mf < 4; ++mf) {
#pragma unroll
        for (int reg = 0; reg < 4; ++reg) {
            float p = 0.f;
#pragma unroll
            for (int nf = 0; nf < 4; ++nf)
                p += va_r[nf] * fast_tanh(qp_r[nf] + acc[mf][nf][reg]);
            p += __shfl_xor(p, 1);
            p += __shfl_xor(p, 2);
            p += __shfl_xor(p, 4);
            p += __shfl_xor(p, 8);
            if (lq == 0) smp[wn][wm * 64 + mf * 16 + lh * 4 + reg] = p;
        }
    }
    __syncthreads();
    if (tid < 128) {
        float s = smp[0][tid] + smp[1][tid];
        part_sc[((size_t)nb * B_ + b) * S_ + m0 + tid] = s;
    }
}

// ---------------------------------------------------------------------------
// Kernel 4: merge 4 n-partials (fixed order, deterministic) + softmax -> wts
// ---------------------------------------------------------------------------
__global__ __launch_bounds__(512) void k_softmax(const float* __restrict__ part_sc,
                                                 float* __restrict__ wts) {
    __shared__ float red[8];
    int b = blockIdx.x, tid = threadIdx.x;
    const float* p0 = part_sc + (size_t)b * S_;
    const float* p1 = p0 + (size_t)B_ * S_;
    const float* p2 = p1 + (size_t)B_ * S_;
    const float* p3 = p2 + (size_t)B_ * S_;
    float v[8];
    float m = -1e30f;
#pragma unroll
    for (int i = 0; i < 8; ++i) {
        int s = tid + i * 512;
        v[i] = ((p0[s] + p1[s]) + (p2[s] + p3[s]));
        m = fmaxf(m, v[i]);
    }
#pragma unroll
    for (int o = 1; o < 64; o <<= 1) m = fmaxf(m, __shfl_xor(m, o));
    if ((tid & 63) == 0) red[tid >> 6] = m;
    __syncthreads();
    m = red[0];
#pragma unroll
    for (int w = 1; w < 8; ++w) m = fmaxf(m, red[w]);
    float sum = 0.f;
#pragma unroll
    for (int i = 0; i < 8; ++i) {
        v[i] = __expf(v[i] - m);
        sum += v[i];
    }
#pragma unroll
    for (int o = 1; o < 64; o <<= 1) sum += __shfl_xor(sum, o);
    __syncthreads();
    if ((tid & 63) == 0) red[tid >> 6] = sum;
    __syncthreads();
    float tot = 0.f;
#pragma unroll
    for (int w = 0; w < 8; ++w) tot += red[w];
    float inv = 1.f / tot;
#pragma unroll
    for (int i = 0; i < 8; ++i) wts[(size_t)b * S_ + tid + i * 512] = v[i] * inv;
}

// ---------------------------------------------------------------------------
// Kernel 5: partial context over 128-row chunks. grid (32,32), block (512)
// ---------------------------------------------------------------------------
__global__ __launch_bounds__(512) void k_ctx_part(const float* __restrict__ keys,
                                                  const float* __restrict__ wts,
                                                  float* __restrict__ part) {
    int c = blockIdx.x, b = blockIdx.y, h = threadIdx.x;
    const float* wrow = wts + (size_t)b * S_ + c * 128;
    const float* kbase = keys + ((size_t)b * S_ + c * 128) * H_ + h;
    float acc = 0.f;
#pragma unroll 8
    for (int s = 0; s < 128; ++s)
        acc = fmaf(wrow[s], kbase[(size_t)s * H_], acc);
    part[((size_t)c * B_ + b) * H_ + h] = acc;
}

// ---------------------------------------------------------------------------
// Kernel 6: reduce partials -> context. grid (32), block (512)
// ---------------------------------------------------------------------------
__global__ __launch_bounds__(512) void k_ctx_reduce(const float* __restrict__ part,
                                                    float* __restrict__ ctx) {
    int b = blockIdx.x, h = threadIdx.x;
    float s = 0.f;
#pragma unroll
    for (int c = 0; c < 32; ++c) s += part[((size_t)c * B_ + b) * H_ + h];
    ctx[(size_t)b * H_ + h] = s;
}

// ---------------------------------------------------------------------------
extern "C" void kernel_launch(void* const* d_in, const int* in_sizes, int n_in,
                              void* d_out, int out_size, void* d_ws, size_t ws_size,
                              hipStream_t stream) {
    const float* query = (const float*)d_in[0];
    const float* keys  = (const float*)d_in[1];
    const float* Wa    = (const float*)d_in[2];
    const float* Ua    = (const float*)d_in[3];
    const float* Va    = (const float*)d_in[4];

    float* out = (float*)d_out;
    float* ctx = out;             // [32,512]
    float* wts = out + B_ * H_;   // [32,4096]

    char* ws = (char*)d_ws;
    unsigned short* ua_t = (unsigned short*)ws;                     // 512 KB
    float* qproj   = (float*)(ws + 524288);                         // 64 KB
    float* part_sc = (float*)(ws + 524288 + 65536);                 // 2 MB
    float* part_cx = (float*)(ws + 524288 + 65536 + 2097152);       // 2 MB

    k_prep_ua<<<dim3(16, 16), dim3(32, 8), 0, stream>>>(Ua, ua_t);
    k_qproj<<<dim3(32), dim3(512), 0, stream>>>(query, Wa, qproj);
    k_scores<<<dim3(4096), dim3(256), 0, stream>>>(keys, ua_t, qproj, Va, part_sc);
    k_softmax<<<dim3(32), dim3(512), 0, stream>>>(part_sc, wts);
    k_ctx_part<<<dim3(32, 32), dim3(512), 0, stream>>>(keys, wts, part_cx);
    k_ctx_reduce<<<dim3(32), dim3(512), 0, stream>>>(part_cx, ctx);
}

// Round 7
// 216.525 us; speedup vs baseline: 1.1366x; 1.1366x over previous
//
#include <hip/hip_runtime.h>
#include <hip/hip_bf16.h>

#define B_ 32
#define S_ 4096
#define H_ 512

typedef short bf16x8 __attribute__((ext_vector_type(8)));
typedef float f32x4 __attribute__((ext_vector_type(4)));

__device__ inline unsigned short f2bf(float x) {
    unsigned u = __float_as_uint(x);
    return (unsigned short)((u + 0x7fffu + ((u >> 16) & 1u)) >> 16);
}

// native packed f32x2 -> bf16x2 (v_cvt_pk_bf16_f32 via compiler, RNE)
__device__ __forceinline__ unsigned cvt2(float a, float b) {
    __hip_bfloat162 h = __float22bfloat162_rn(float2{a, b});
    return *reinterpret_cast<unsigned*>(&h);
}

__device__ inline float fast_tanh(float x) {
    float e = __expf(2.f * x);
    return 1.f - 2.f / (e + 1.f);
}

// async global->LDS, 16B per lane; lds base must be wave-uniform (HW adds lane*16)
__device__ __forceinline__ void stage16(const void* g, void* lds_base) {
    __builtin_amdgcn_global_load_lds(
        (const __attribute__((address_space(1))) unsigned char*)g,
        (__attribute__((address_space(3))) unsigned char*)lds_base, 16, 0, 0);
}

// ---------------------------------------------------------------------------
// Kernel 1: transpose+convert Ua[h][d] (f32) -> ua_t[d][h] (bf16, row-major)
// ---------------------------------------------------------------------------
__global__ void k_prep_ua(const float* __restrict__ Ua,
                          unsigned short* __restrict__ ua_t) {
    __shared__ float tile[32][33];
    int h0 = blockIdx.x * 32, d0 = blockIdx.y * 32;
    int tx = threadIdx.x, ty = threadIdx.y;
#pragma unroll
    for (int j = 0; j < 4; ++j)
        tile[ty + j * 8][tx] = Ua[(size_t)(h0 + ty + j * 8) * H_ + d0 + tx];
    __syncthreads();
#pragma unroll
    for (int j = 0; j < 4; ++j) {
        int dl = ty + j * 8;
        ua_t[(size_t)(d0 + dl) * H_ + h0 + tx] = f2bf(tile[tx][dl]);
    }
}

// ---------------------------------------------------------------------------
// Kernel 2: q_proj[b][d] = sum_h query[b][h] * Wa[h][d]   (fp32, tiny)
// ---------------------------------------------------------------------------
__global__ __launch_bounds__(512) void k_qproj(const float* __restrict__ query,
                                               const float* __restrict__ Wa,
                                               float* __restrict__ qproj) {
    __shared__ float q[H_];
    int b = blockIdx.x, d = threadIdx.x;
    q[d] = query[(size_t)b * H_ + d];
    __syncthreads();
    float acc = 0.f;
    for (int h = 0; h < H_; ++h)
        acc = fmaf(q[h], Wa[(size_t)h * H_ + d], acc);
    qproj[(size_t)b * H_ + d] = acc;
}

// ---------------------------------------------------------------------------
// Kernel 3: partial scores. 256 thr / 4 waves (2x2, wave tile 64x64),
// block 128(M) x 128(N), BK=64, 8 K-iters. BOTH A and B LDS double-buffered,
// ONE barrier per iter. A staged coalesced: thread t sweep j reads row
// j*16+(t>>4), floats (t&15)*4..+4 -> wave instr = 1KB contiguous (16 lines,
// minimal) -> native cvt_pk -> ds_write_b64 (XOR-swizzled). B via
// global_load_lds (per-lane row + swizzle in global src; LDS linear).
// flat grid 4096 = (b:32) x (m:32) x (nb:4), XCD-swizzled, nb fastest.
// ---------------------------------------------------------------------------
__global__ __launch_bounds__(256, 2) void k_scores(
    const float* __restrict__ keys, const unsigned short* __restrict__ ua_t,
    const float* __restrict__ qproj, const float* __restrict__ Va,
    float* __restrict__ part_sc) {
    __shared__ __align__(16) unsigned char As[2][16384];   // [128 rows][128 B] swizzled
    __shared__ __align__(16) unsigned char Bs[2][16384];
    __shared__ float smp[2][128];

    int tid = threadIdx.x;
    int wave = tid >> 6, lane = tid & 63;
    int lq = lane & 15, lh = lane >> 4;
    int wm = wave >> 1, wn = wave & 1;   // 2x2 wave grid, each 64x64

    // bijective XCD swizzle (4096 % 8 == 0); nb fastest so the 4 n-tiles
    // re-reading the same keys rows share one XCD's L2.
    int logical = (blockIdx.x & 7) * 512 + (blockIdx.x >> 3);
    int b  = logical >> 7;
    int m0 = ((logical >> 2) & 31) * 128;
    int nb = logical & 3;

    const float* keysb = keys + (size_t)b * S_ * H_;

    // --- A staging map (coalesced): sweep j covers rows j*16..j*16+15.
    // thread t: row_in_sweep = t>>4, float col = (t&15)*4.
    int arow_t = tid >> 4;               // 0..15
    int acolf  = (tid & 15) * 4;         // 0..60
    const float* aptr = keysb + (size_t)(m0 + arow_t) * H_ + acolf;
    // LDS write byte offset (row r = j*16+arow_t; (r&7) == (arow_t&7)):
    unsigned awb = (unsigned)(arow_t * 128 + (((tid & 15) * 8) ^ ((arow_t & 7) << 4)));

    // --- B staging map: 4 gload_lds per wave; issue j=wave*4+i covers rows
    // 8j..8j+7. Per-lane global addr = row (8j + lane>>3), col (lane&7)*16,
    // XOR-swizzled by ((lane>>3)<<4). LDS dest linear.
    int rbl = lane >> 3;
    unsigned cbb = (unsigned)(((lane & 7) * 16) ^ (rbl << 4));
    const unsigned char* uab = (const unsigned char*)ua_t;
    const unsigned char* bsrc[4];
    unsigned bdst[4];
#pragma unroll
    for (int i = 0; i < 4; ++i) {
        int j = wave * 4 + i;
        bsrc[i] = uab + ((size_t)(nb * 128 + 8 * j + rbl)) * 1024 + cbb;
        bdst[i] = (unsigned)(j * 1024);
    }

    f32x4 acc[4][4];
#pragma unroll
    for (int i = 0; i < 4; ++i)
#pragma unroll
        for (int j = 0; j < 4; ++j) acc[i][j] = (f32x4){0.f, 0.f, 0.f, 0.f};

    // ---- prologue: stage tile 0 into buffer 0
#pragma unroll
    for (int i = 0; i < 4; ++i) stage16(bsrc[i], &Bs[0][bdst[i]]);
    {
        float4 a0[8];
#pragma unroll
        for (int j = 0; j < 8; ++j)
            a0[j] = *(const float4*)(aptr + (size_t)j * 16 * H_);
#pragma unroll
        for (int j = 0; j < 8; ++j) {
            uint2 w;
            w.x = cvt2(a0[j].x, a0[j].y);
            w.y = cvt2(a0[j].z, a0[j].w);
            *(uint2*)(&As[0][0] + awb + j * 2048) = w;
        }
    }
    __syncthreads();

#pragma unroll
    for (int t = 0; t < 8; ++t) {
        const int cur = t & 1, nxt = cur ^ 1;
        float4 ar[8];
        // 1) issue next-tile loads: fly across the whole compute phase
        if (t < 7) {
#pragma unroll
            for (int i = 0; i < 4; ++i)
                stage16(bsrc[i] + (t + 1) * 128, &Bs[nxt][bdst[i]]);
#pragma unroll
            for (int j = 0; j < 8; ++j)
                ar[j] = *(const float4*)(aptr + (size_t)j * 16 * H_ + (t + 1) * 64);
        }
        // 2) compute tile t: 16 ds_read_b128 -> 32 MFMAs per wave
#pragma unroll
        for (int ks = 0; ks < 2; ++ks) {
            bf16x8 af[4], bv[4];
            unsigned koff = (unsigned)(ks * 64 + lh * 16);
#pragma unroll
            for (int mf = 0; mf < 4; ++mf) {
                unsigned R = (unsigned)(wm * 64 + mf * 16 + lq);
                af[mf] = *(const bf16x8*)(&As[cur][0] + R * 128 + (koff ^ ((R & 7) << 4)));
            }
#pragma unroll
            for (int nf = 0; nf < 4; ++nf) {
                unsigned R = (unsigned)(wn * 64 + nf * 16 + lq);
                bv[nf] = *(const bf16x8*)(&Bs[cur][0] + R * 128 + (koff ^ ((R & 7) << 4)));
            }
#pragma unroll
            for (int mf = 0; mf < 4; ++mf)
#pragma unroll
                for (int nf = 0; nf < 4; ++nf)
                    acc[mf][nf] = __builtin_amdgcn_mfma_f32_16x16x32_bf16(
                        af[mf], bv[nf], acc[mf][nf], 0, 0, 0);
        }
        // 3) convert + write A(t+1) into As[nxt] (A-load latency hidden by 2)
        if (t < 7) {
#pragma unroll
            for (int j = 0; j < 8; ++j) {
                uint2 w;
                w.x = cvt2(ar[j].x, ar[j].y);
                w.y = cvt2(ar[j].z, ar[j].w);
                *(uint2*)(&As[nxt][0] + awb + j * 2048) = w;
            }
        }
        // 4) ONE barrier per iter: drains B-gload_lds vmcnt + A ds_writes
        __syncthreads();
    }

    // epilogue: partial score over this block's 128 d-columns
    float va_r[4], qp_r[4];
#pragma unroll
    for (int nf = 0; nf < 4; ++nf) {
        int n = nb * 128 + wn * 64 + nf * 16 + lq;
        va_r[nf] = Va[n];
        qp_r[nf] = qproj[(size_t)b * H_ + n];
    }
#pragma unroll
    for (int mf = 0; mf < 4; ++mf) {
#pragma unroll
        for (int reg = 0; reg < 4; ++reg) {
            float p = 0.f;
#pragma unroll
            for (int nf = 0; nf < 4; ++nf)
                p += va_r[nf] * fast_tanh(qp_r[nf] + acc[mf][nf][reg]);
            p += __shfl_xor(p, 1);
            p += __shfl_xor(p, 2);
            p += __shfl_xor(p, 4);
            p += __shfl_xor(p, 8);
            if (lq == 0) smp[wn][wm * 64 + mf * 16 + lh * 4 + reg] = p;
        }
    }
    __syncthreads();
    if (tid < 128) {
        float s = smp[0][tid] + smp[1][tid];
        part_sc[((size_t)nb * B_ + b) * S_ + m0 + tid] = s;
    }
}

// ---------------------------------------------------------------------------
// Kernel 4: merge 4 n-partials (fixed order, deterministic) + softmax -> wts
// ---------------------------------------------------------------------------
__global__ __launch_bounds__(512) void k_softmax(const float* __restrict__ part_sc,
                                                 float* __restrict__ wts) {
    __shared__ float red[8];
    int b = blockIdx.x, tid = threadIdx.x;
    const float* p0 = part_sc + (size_t)b * S_;
    const float* p1 = p0 + (size_t)B_ * S_;
    const float* p2 = p1 + (size_t)B_ * S_;
    const float* p3 = p2 + (size_t)B_ * S_;
    float v[8];
    float m = -1e30f;
#pragma unroll
    for (int i = 0; i < 8; ++i) {
        int s = tid + i * 512;
        v[i] = ((p0[s] + p1[s]) + (p2[s] + p3[s]));
        m = fmaxf(m, v[i]);
    }
#pragma unroll
    for (int o = 1; o < 64; o <<= 1) m = fmaxf(m, __shfl_xor(m, o));
    if ((tid & 63) == 0) red[tid >> 6] = m;
    __syncthreads();
    m = red[0];
#pragma unroll
    for (int w = 1; w < 8; ++w) m = fmaxf(m, red[w]);
    float sum = 0.f;
#pragma unroll
    for (int i = 0; i < 8; ++i) {
        v[i] = __expf(v[i] - m);
        sum += v[i];
    }
#pragma unroll
    for (int o = 1; o < 64; o <<= 1) sum += __shfl_xor(sum, o);
    __syncthreads();
    if ((tid & 63) == 0) red[tid >> 6] = sum;
    __syncthreads();
    float tot = 0.f;
#pragma unroll
    for (int w = 0; w < 8; ++w) tot += red[w];
    float inv = 1.f / tot;
#pragma unroll
    for (int i = 0; i < 8; ++i) wts[(size_t)b * S_ + tid + i * 512] = v[i] * inv;
}

// ---------------------------------------------------------------------------
// Kernel 5: partial context over 128-row chunks. grid (32,32), block (512)
// ---------------------------------------------------------------------------
__global__ __launch_bounds__(512) void k_ctx_part(const float* __restrict__ keys,
                                                  const float* __restrict__ wts,
                                                  float* __restrict__ part) {
    int c = blockIdx.x, b = blockIdx.y, h = threadIdx.x;
    const float* wrow = wts + (size_t)b * S_ + c * 128;
    const float* kbase = keys + ((size_t)b * S_ + c * 128) * H_ + h;
    float acc = 0.f;
#pragma unroll 8
    for (int s = 0; s < 128; ++s)
        acc = fmaf(wrow[s], kbase[(size_t)s * H_], acc);
    part[((size_t)c * B_ + b) * H_ + h] = acc;
}

// ---------------------------------------------------------------------------
// Kernel 6: reduce partials -> context. grid (32), block (512)
// ---------------------------------------------------------------------------
__global__ __launch_bounds__(512) void k_ctx_reduce(const float* __restrict__ part,
                                                    float* __restrict__ ctx) {
    int b = blockIdx.x, h = threadIdx.x;
    float s = 0.f;
#pragma unroll
    for (int c = 0; c < 32; ++c) s += part[((size_t)c * B_ + b) * H_ + h];
    ctx[(size_t)b * H_ + h] = s;
}

// ---------------------------------------------------------------------------
extern "C" void kernel_launch(void* const* d_in, const int* in_sizes, int n_in,
                              void* d_out, int out_size, void* d_ws, size_t ws_size,
                              hipStream_t stream) {
    const float* query = (const float*)d_in[0];
    const float* keys  = (const float*)d_in[1];
    const float* Wa    = (const float*)d_in[2];
    const float* Ua    = (const float*)d_in[3];
    const float* Va    = (const float*)d_in[4];

    float* out = (float*)d_out;
    float* ctx = out;             // [32,512]
    float* wts = out + B_ * H_;   // [32,4096]

    char* ws = (char*)d_ws;
    unsigned short* ua_t = (unsigned short*)ws;                     // 512 KB
    float* qproj   = (float*)(ws + 524288);                         // 64 KB
    float* part_sc = (float*)(ws + 524288 + 65536);                 // 2 MB
    float* part_cx = (float*)(ws + 524288 + 65536 + 2097152);       // 2 MB

    k_prep_ua<<<dim3(16, 16), dim3(32, 8), 0, stream>>>(Ua, ua_t);
    k_qproj<<<dim3(32), dim3(512), 0, stream>>>(query, Wa, qproj);
    k_scores<<<dim3(4096), dim3(256), 0, stream>>>(keys, ua_t, qproj, Va, part_sc);
    k_softmax<<<dim3(32), dim3(512), 0, stream>>>(part_sc, wts);
    k_ctx_part<<<dim3(32, 32), dim3(512), 0, stream>>>(keys, wts, part_cx);
    k_ctx_reduce<<<dim3(32), dim3(512), 0, stream>>>(part_cx, ctx);
}